// Round 7
// baseline (921.827 us; speedup 1.0000x reference)
//
#include <hip/hip_runtime.h>
#include <hip/hip_bf16.h>

// Problem constants (from setup_inputs)
#define N_EMB   6272
#define M_BANK  32768
#define D_DIM   128
#define KP      128      // packed rows: bf16 hi only
#define BATCH   8
#define P_PATCH 784      // 6272 / 8
#define GRID_WH 28
#define OUT_WH  224
#define KNN     9
#define KSIZE   33
#define KRAD    16
#define CANDCAP 64
#define SEL_MARGIN 0.2f  // certificate: > 2.6x worst-case bf16-hi score error

typedef unsigned long long ull;
typedef short bf16x8 __attribute__((ext_vector_type(8)));
typedef float f32x4  __attribute__((ext_vector_type(4)));

// ---------------- workspace layout (bytes) ----------------
#define WS_MINPACK 0          // u64[6272]        -> 50176
#define WS_X2      50176      // f32[6272]        -> 75264
#define WS_Y2      75264      // f32[32768]       -> 206336
#define WS_PSCORE  206336     // f32[6272]        -> 231424
#define WS_BSCORE  231424     // f32[8]
#define WS_BMAXP   231456     // i32[8]
#define WS_BNN     231488     // i32[8]
#define WS_CAND    231552     // u64[8*32*9]      -> 249984
#define WS_CLIST   249984     // i32[8*64]        -> 252032
#define WS_CCNT    252032     // i32[8]           -> 252064
#define WS_EMIN    252096     // u64[8*64]        -> 256192
#define WS_DNN     256256     // f32[8*32768]     -> 1304832
#define WS_APK     1304832    // u16[6272*128]    -> 2910464  (16B aligned)
#define WS_BPK     2910464    // u16[32768*128]   -> 11299072 (16B aligned)

__device__ __forceinline__ ull umin64(ull a, ull b) { return a < b ? a : b; }
__device__ __forceinline__ ull umax64(ull a, ull b) { return a > b ? a : b; }

__device__ __forceinline__ void gload_lds16(const void* g, void* l) {
    __builtin_amdgcn_global_load_lds(
        (const __attribute__((address_space(1))) void*)g,
        (__attribute__((address_space(3))) void*)l, 16, 0, 0);
}

// ---------------------------------------------------------------------------
// Kernel 0 (prep): bf16-hi pack + sum-of-squares + minpack init.
// One wave per row.
// ---------------------------------------------------------------------------
__global__ __launch_bounds__(256) void prep_kernel(
    const float* __restrict__ emb, const float* __restrict__ bank,
    unsigned short* __restrict__ Apk, unsigned short* __restrict__ Bpk,
    float* __restrict__ x2, float* __restrict__ y2, ull* __restrict__ minpack)
{
    const int tid = threadIdx.x;
    int gi = blockIdx.x * 256 + tid;
    if (gi < N_EMB) minpack[gi] = ~0ull;

    const int w    = blockIdx.x * 4 + (tid >> 6);
    const int lane = tid & 63;
    const float* src;
    unsigned short* dst;
    float* sq;
    if (w < N_EMB) {
        src = emb + (size_t)w * D_DIM;
        dst = Apk + (size_t)w * KP;
        sq  = x2 + w;
    } else {
        int m = w - N_EMB;             // grid sized exactly -> m < M_BANK
        src = bank + (size_t)m * D_DIM;
        dst = Bpk + (size_t)m * KP;
        sq  = y2 + m;
    }
    float2 v = *(const float2*)&src[2 * lane];
    __hip_bfloat16 h0 = __float2bfloat16(v.x);
    __hip_bfloat16 h1 = __float2bfloat16(v.y);
    unsigned hb0 = *(unsigned short*)&h0, hb1 = *(unsigned short*)&h1;
    *(unsigned*)&dst[2 * lane] = hb0 | (hb1 << 16);

    float s = fmaf(v.x, v.x, v.y * v.y);
    #pragma unroll
    for (int off = 32; off > 0; off >>= 1) s += __shfl_down(s, off, 64);
    if (lane == 0) *sq = s;
}

// ---------------------------------------------------------------------------
// Kernel 1: single-pass bf16-hi MFMA distance + fused min/argmin (approx).
// 128x128 tile, 16x16x32 MFMA, K=128 (4 k-iters), R3-proven structure.
// ---------------------------------------------------------------------------
__global__ __launch_bounds__(256) void mfma_min_kernel(
    const unsigned short* __restrict__ Apk, const unsigned short* __restrict__ Bpk,
    const float* __restrict__ x2, const float* __restrict__ y2,
    ull* __restrict__ minpack)
{
    __shared__ __align__(16) unsigned short Asm_[128 * 32];  // 8 KB
    __shared__ __align__(16) unsigned short Bsm_[128 * 32];  // 8 KB

    const int tid  = threadIdx.x;
    const int lane = tid & 63;
    const int wave = tid >> 6;
    const int wr = wave >> 1, wc = wave & 1;
    const int n0 = blockIdx.y * 128;
    const int m0 = blockIdx.x * 128;

    const int srow = tid >> 2;   // 0..63 staging row
    const int sseg = tid & 3;    // 16B segment within 64B row-chunk

    const int qa = lane >> 4;    // k-quad
    const int ra = lane & 15;    // row-in-frag / col-in-C

    f32x4 acc[4][4];
    #pragma unroll
    for (int i = 0; i < 4; ++i)
        #pragma unroll
        for (int j = 0; j < 4; ++j)
            acc[i][j] = (f32x4){0.f, 0.f, 0.f, 0.f};

    for (int ks = 0; ks < KP; ks += 32) {
        __syncthreads();
        const size_t gA = (size_t)(n0 + srow) * KP + ks + sseg * 8;
        const size_t gB = (size_t)(m0 + srow) * KP + ks + sseg * 8;
        gload_lds16(Apk + gA,            &Asm_[srow * 32 + sseg * 8]);
        gload_lds16(Apk + gA + 64 * KP,  &Asm_[(srow + 64) * 32 + sseg * 8]);
        gload_lds16(Bpk + gB,            &Bsm_[srow * 32 + sseg * 8]);
        gload_lds16(Bpk + gB + 64 * KP,  &Bsm_[(srow + 64) * 32 + sseg * 8]);
        __syncthreads();

        bf16x8 af[4], bfr[4];
        #pragma unroll
        for (int i = 0; i < 4; ++i)
            af[i] = *(const bf16x8*)&Asm_[(wr * 64 + i * 16 + ra) * 32 + qa * 8];
        #pragma unroll
        for (int j = 0; j < 4; ++j)
            bfr[j] = *(const bf16x8*)&Bsm_[(wc * 64 + j * 16 + ra) * 32 + qa * 8];
        #pragma unroll
        for (int i = 0; i < 4; ++i)
            #pragma unroll
            for (int j = 0; j < 4; ++j)
                acc[i][j] = __builtin_amdgcn_mfma_f32_16x16x32_bf16(af[i], bfr[j], acc[i][j], 0, 0, 0);
    }

    // ---- epilogue: d2 = x2 + y2 - 2*dot, clamp, pack, reduce ----
    float y2v[4];
    #pragma unroll
    for (int j = 0; j < 4; ++j) y2v[j] = y2[m0 + wc * 64 + j * 16 + ra];

    __syncthreads();                 // all frag reads done; reuse Asm_ as red
    ull* red = (ull*)Asm_;           // [128 rows][2 col-halves]
    #pragma unroll
    for (int i = 0; i < 4; ++i) {
        #pragma unroll
        for (int r = 0; r < 4; ++r) {
            const int rowl = wr * 64 + i * 16 + qa * 4 + r;
            const float xv = x2[n0 + rowl];
            ull mn = ~0ull;
            #pragma unroll
            for (int j = 0; j < 4; ++j) {
                const int m = m0 + wc * 64 + j * 16 + ra;
                float d2 = fmaf(-2.0f, acc[i][j][r], xv + y2v[j]);
                d2 = fmaxf(d2, 0.0f);
                ull p = ((ull)__float_as_uint(d2) << 32) | (unsigned)m;
                mn = umin64(mn, p);
            }
            #pragma unroll
            for (int s = 1; s < 16; s <<= 1)
                mn = umin64(mn, (ull)__shfl_xor(mn, s, 64));
            if (ra == 0) red[rowl * 2 + wc] = mn;
        }
    }
    __syncthreads();
    if (tid < 128)
        atomicMin(&minpack[n0 + tid], umin64(red[tid * 2], red[tid * 2 + 1]));
}

// ---------------------------------------------------------------------------
// Kernel 2 (select): writes approx pscore (map path); finds per-batch approx
// max score; selects ALL patches within SEL_MARGIN of it (certified superset
// of the exact argmax; typically 2-5, cap 64); inits exact-min slots.
// ---------------------------------------------------------------------------
__global__ __launch_bounds__(256) void select_kernel(
    const ull* __restrict__ minpack, float* __restrict__ pscore,
    int* __restrict__ clist, int* __restrict__ ccnt, ull* __restrict__ emin)
{
    __shared__ ull red[256];
    __shared__ int scnt;
    __shared__ float smax;
    const int b = blockIdx.x, tid = threadIdx.x;

    if (tid < CANDCAP) emin[b * CANDCAP + tid] = ~0ull;
    if (tid == 0) scnt = 0;

    ull local = 0;
    for (int p = tid; p < P_PATCH; p += 256) {
        ull mp = minpack[b * P_PATCH + p];
        unsigned d2b = (unsigned)(mp >> 32);
        pscore[b * P_PATCH + p] = sqrtf(__uint_as_float(d2b));
        local = umax64(local, ((ull)d2b << 32) | (unsigned)(p ^ 0xFFFFFFFFu));
    }
    red[tid] = local;
    __syncthreads();
    for (int s = 128; s > 0; s >>= 1) {
        if (tid < s) red[tid] = umax64(red[tid], red[tid + s]);
        __syncthreads();
    }
    if (tid == 0) smax = sqrtf(__uint_as_float((unsigned)(red[0] >> 32)));
    __syncthreads();

    float thr = smax - SEL_MARGIN;
    float thr2 = thr > 0.0f ? thr * thr : 0.0f;
    for (int p = tid; p < P_PATCH; p += 256) {
        float d2 = __uint_as_float((unsigned)(minpack[b * P_PATCH + p] >> 32));
        if (d2 >= thr2) {
            int idx = atomicAdd(&scnt, 1);
            if (idx < CANDCAP) clist[b * CANDCAP + idx] = p;
        }
    }
    __syncthreads();
    if (tid == 0) ccnt[b] = min(scnt, CANDCAP);
}

// ---------------------------------------------------------------------------
// Kernel 3 (repair): exact fp32 min/argmin over the full bank for each
// candidate patch. Grid (32 chunks, 8 batches); atomicMin into emin slots.
// ---------------------------------------------------------------------------
__global__ __launch_bounds__(256) void repair_kernel(
    const float* __restrict__ emb, const float* __restrict__ bank,
    const float* __restrict__ x2, const float* __restrict__ y2,
    const int* __restrict__ clist, const int* __restrict__ ccnt,
    ull* __restrict__ emin)
{
    __shared__ float cv[CANDCAP * D_DIM];   // 32 KB
    __shared__ float cx2[CANDCAP];
    __shared__ ull sred[4 * CANDCAP];       // per-wave per-cand running min
    const int tid = threadIdx.x;
    const int ch = blockIdx.x, b = blockIdx.y;
    const int cnt = ccnt[b];

    for (int i = tid; i < cnt * D_DIM; i += 256) {
        int slot = i >> 7, d = i & 127;
        cv[i] = emb[((size_t)b * P_PATCH + clist[b * CANDCAP + slot]) * D_DIM + d];
    }
    if (tid < cnt) cx2[tid] = x2[b * P_PATCH + clist[b * CANDCAP + tid]];
    sred[tid & 255] = ~0ull;      // 256 covers 4*CANDCAP
    __syncthreads();

    const int w = tid >> 6, lane = tid & 63;
    for (int rep = 0; rep < 256; ++rep) {
        const int m = ch * 1024 + rep * 4 + w;
        float2 v = *(const float2*)&bank[(size_t)m * D_DIM + 2 * lane];
        for (int c = 0; c < cnt; ++c) {
            float s = fmaf(v.x, cv[c * D_DIM + 2 * lane], v.y * cv[c * D_DIM + 2 * lane + 1]);
            #pragma unroll
            for (int off = 32; off > 0; off >>= 1) s += __shfl_down(s, off, 64);
            if (lane == 0) {
                float d2 = fmaxf(cx2[c] + y2[m] - 2.0f * s, 0.0f);
                ull pk = ((ull)__float_as_uint(d2) << 32) | (unsigned)m;
                sred[w * CANDCAP + c] = umin64(sred[w * CANDCAP + c], pk);
            }
        }
    }
    __syncthreads();
    if (tid < cnt) {
        ull v = umin64(umin64(sred[tid], sred[CANDCAP + tid]),
                       umin64(sred[2 * CANDCAP + tid], sred[3 * CANDCAP + tid]));
        atomicMin(&emin[b * CANDCAP + tid], v);
    }
}

// ---------------------------------------------------------------------------
// Kernel 4 (scorefix): exact per-batch argmax among candidates -> bscore,
// bmaxp, bnn. One wave per batch.
// ---------------------------------------------------------------------------
__global__ __launch_bounds__(64) void scorefix_kernel(
    const int* __restrict__ clist, const int* __restrict__ ccnt,
    const ull* __restrict__ emin,
    float* __restrict__ bscore, int* __restrict__ bmaxp, int* __restrict__ bnn)
{
    const int b = blockIdx.x, tid = threadIdx.x;
    const int cnt = ccnt[b];
    ull local = 0;
    ull mypk = 0;
    if (tid < cnt) {
        mypk = emin[b * CANDCAP + tid];
        unsigned scb = __float_as_uint(sqrtf(__uint_as_float((unsigned)(mypk >> 32))));
        local = ((ull)scb << 32) | (unsigned)(clist[b * CANDCAP + tid] ^ 0xFFFFFFFFu);
    }
    #pragma unroll
    for (int off = 32; off > 0; off >>= 1) local = umax64(local, (ull)__shfl_down(local, off, 64));
    ull win = (ull)__shfl(local, 0, 64);
    int p = (int)(((unsigned)(win & 0xFFFFFFFFu)) ^ 0xFFFFFFFFu);
    if (tid == 0) {
        bscore[b] = __uint_as_float((unsigned)(win >> 32));
        bmaxp[b]  = p;
    }
    if (tid < cnt && clist[b * CANDCAP + tid] == p)
        bnn[b] = (int)(mypk & 0xFFFFFFFFu);
}

// ---------------------------------------------------------------------------
// Kernel 5: d_nn = dist(nn_sample[b], memory_bank) -> (8, M). 8192 blocks.
// ---------------------------------------------------------------------------
__global__ __launch_bounds__(256) void dnn_kernel(
    const float* __restrict__ bank, const float* __restrict__ y2,
    const int* __restrict__ bnn, float* __restrict__ dnn)
{
    __shared__ float nn[BATCH][D_DIM];
    __shared__ float nny2[BATCH];
    int tid = threadIdx.x;
    for (int i = tid; i < BATCH * D_DIM; i += 256) {
        int b = i >> 7, d = i & 127;
        nn[b][d] = bank[(size_t)bnn[b] * D_DIM + d];
    }
    if (tid < BATCH) nny2[tid] = y2[bnn[tid]];
    __syncthreads();

    int w = tid >> 6, lane = tid & 63;
    int m = blockIdx.x * 4 + w;
    float2 v = *(const float2*)&bank[(size_t)m * D_DIM + 2 * lane];
    float part[BATCH];
    #pragma unroll
    for (int b = 0; b < BATCH; ++b)
        part[b] = fmaf(v.x, nn[b][2 * lane], v.y * nn[b][2 * lane + 1]);
    #pragma unroll
    for (int b = 0; b < BATCH; ++b) {
        float s = part[b];
        #pragma unroll
        for (int off = 32; off > 0; off >>= 1) s += __shfl_down(s, off, 64);
        if (lane == 0) {
            float d2 = nny2[b] + y2[m] - 2.0f * s;
            dnn[b * M_BANK + m] = sqrtf(fmaxf(d2, 0.0f));
        }
    }
}

// ---------------------------------------------------------------------------
// Kernel 6: per-(batch, 1024-chunk) local top-9 of d_nn.
// ---------------------------------------------------------------------------
__global__ __launch_bounds__(256) void topk_part_kernel(
    const float* __restrict__ dnn, ull* __restrict__ cand)
{
    __shared__ ull vals[1024];
    __shared__ ull red[256];
    const int tid = threadIdx.x;
    const int b = blockIdx.y, ch = blockIdx.x;
    const int base = ch * 1024;

    #pragma unroll
    for (int j = 0; j < 4; ++j) {
        int i = base + tid + j * 256;
        vals[tid + j * 256] = ((ull)__float_as_uint(dnn[b * M_BANK + i]) << 32) | (unsigned)i;
    }
    __syncthreads();

    for (int k = 0; k < KNN; ++k) {
        ull local = vals[tid];
        #pragma unroll
        for (int j = 1; j < 4; ++j) local = umin64(local, vals[tid + j * 256]);
        red[tid] = local;
        __syncthreads();
        for (int s = 128; s > 0; s >>= 1) {
            if (tid < s) red[tid] = umin64(red[tid], red[tid + s]);
            __syncthreads();
        }
        ull win = red[0];
        if (tid == 0) cand[(b * 32 + ch) * KNN + k] = win;
        #pragma unroll
        for (int j = 0; j < 4; ++j)
            if (vals[tid + j * 256] == win) vals[tid + j * 256] = ~0ull;
        __syncthreads();
    }
}

// ---------------------------------------------------------------------------
// Kernel 7 (role-branched): blocks 0..7 = final top-9 + rescore -> out[0..7];
// blocks 8..63 = fused resize+blur bands -> out[8..].
// ---------------------------------------------------------------------------
__device__ __forceinline__ int refl224(int i) {
    if (i < 0) i = -i;
    if (i >= OUT_WH) i = 2 * (OUT_WH - 1) - i;
    return i;
}

__global__ __launch_bounds__(256) void final_blur_kernel(
    const ull* __restrict__ cand,
    const float* __restrict__ emb, const float* __restrict__ bank,
    const float* __restrict__ x2, const float* __restrict__ y2,
    const float* __restrict__ bscore, const int* __restrict__ bmaxp,
    const float* __restrict__ pscore, float* __restrict__ out)
{
    __shared__ __align__(16) char smem_raw[57344];
    const int tid = threadIdx.x;

    if (blockIdx.x < 8) {
        // ---------------- role A: final top-9 + rescore ----------------
        ull* vals    = (ull*)smem_raw;          // 512
        ull* red     = vals + 512;              // 256
        int* chosen  = (int*)(red + 256);       // KNN (pad 16)
        float* dists = (float*)(chosen + 16);   // KNN
        const int b = blockIdx.x;

        vals[tid]       = (tid < 32 * KNN) ? cand[b * 32 * KNN + tid] : ~0ull;
        vals[tid + 256] = (tid + 256 < 32 * KNN) ? cand[b * 32 * KNN + tid + 256] : ~0ull;
        __syncthreads();

        for (int k = 0; k < KNN; ++k) {
            red[tid] = umin64(vals[tid], vals[tid + 256]);
            __syncthreads();
            for (int s = 128; s > 0; s >>= 1) {
                if (tid < s) red[tid] = umin64(red[tid], red[tid + s]);
                __syncthreads();
            }
            ull win = red[0];
            if (tid == 0) chosen[k] = (int)(win & 0xFFFFFFFFu);
            if (vals[tid] == win) vals[tid] = ~0ull;
            if (vals[tid + 256] == win) vals[tid + 256] = ~0ull;
            __syncthreads();
        }

        const int e = b * P_PATCH + bmaxp[b];
        if (tid < KNN) {
            const float* mf = emb + (size_t)e * D_DIM;
            const float* ms = bank + (size_t)chosen[tid] * D_DIM;
            float dot = 0.0f;
            for (int d = 0; d < D_DIM; ++d) dot = fmaf(mf[d], ms[d], dot);
            float d2 = x2[e] - 2.0f * dot + y2[chosen[tid]];
            dists[tid] = sqrtf(fmaxf(d2, 0.0f));
        }
        __syncthreads();
        if (tid == 0) {
            float mx = dists[0];
            for (int k = 1; k < KNN; ++k) mx = fmaxf(mx, dists[k]);
            float s = 0.0f;
            for (int k = 0; k < KNN; ++k) s += expf(dists[k] - mx);
            float w = 1.0f - expf(dists[0] - mx) / s;
            out[b] = w * bscore[b];
        }
    } else {
        // ---------------- role B: fused resize + separable blur ----------------
        float* q    = (float*)smem_raw;         // 28*224
        float* hq   = q + GRID_WH * OUT_WH;     // 28*224
        float* ps   = hq + GRID_WH * OUT_WH;    // 784
        float* wrow = ps + P_PATCH;             // 32*28
        float* g    = wrow + 32 * GRID_WH;      // 33

        const int idx  = blockIdx.x - 8;
        const int band = idx % 7;               // 0..6
        const int b    = idx / 7;               // 0..7

        if (tid < KSIZE) {
            float x = (tid - KRAD) * 0.25f;     // / SIGMA=4
            g[tid] = __expf(-0.5f * x * x);
        }
        for (int i = tid; i < P_PATCH; i += 256) ps[i] = pscore[b * P_PATCH + i];
        __syncthreads();
        if (tid == 0) {
            float s = 0.0f;
            for (int i = 0; i < KSIZE; ++i) s += g[i];
            float inv = 1.0f / s;
            for (int i = 0; i < KSIZE; ++i) g[i] *= inv;
        }
        __syncthreads();

        for (int i = tid; i < GRID_WH * OUT_WH; i += 256) {
            int gy = i / OUT_WH, x = i - gy * OUT_WH;
            float cx = (2 * x - 7) * 0.0625f;
            int ix = (int)floorf(cx); float fx = cx - ix;
            int x0 = min(max(ix, 0), GRID_WH - 1), x1 = min(max(ix + 1, 0), GRID_WH - 1);
            q[i] = ps[gy * GRID_WH + x0] * (1.0f - fx) + ps[gy * GRID_WH + x1] * fx;
        }

        if (tid < 32) {
            int y = band * 32 + tid;
            for (int gy = 0; gy < GRID_WH; ++gy) wrow[tid * GRID_WH + gy] = 0.0f;
            for (int t = 0; t < KSIZE; ++t) {
                int yy = refl224(y - KRAD + t);
                float cy = (2 * yy - 7) * 0.0625f;
                int iy = (int)floorf(cy); float fy = cy - iy;
                int y0 = min(max(iy, 0), GRID_WH - 1), y1 = min(max(iy + 1, 0), GRID_WH - 1);
                wrow[tid * GRID_WH + y0] += g[t] * (1.0f - fy);
                wrow[tid * GRID_WH + y1] += g[t] * fy;
            }
        }
        __syncthreads();

        for (int i = tid; i < GRID_WH * OUT_WH; i += 256) {
            int gy = i / OUT_WH, x = i - gy * OUT_WH;
            float s = 0.0f;
            #pragma unroll
            for (int t = 0; t < KSIZE; ++t)
                s = fmaf(g[t], q[gy * OUT_WH + refl224(x - KRAD + t)], s);
            hq[i] = s;
        }
        __syncthreads();

        const int yl = tid >> 3;                 // 0..31
        const int xbase = (tid & 7) * 28;        // 8 groups x 28 px
        const int y = band * 32 + yl;
        float* orow = out + BATCH + ((size_t)b * OUT_WH + y) * OUT_WH;
        for (int i = 0; i < 28; ++i) {
            int x = xbase + i;
            float s = 0.0f;
            #pragma unroll
            for (int gy = 0; gy < GRID_WH; ++gy)
                s = fmaf(wrow[yl * GRID_WH + gy], hq[gy * OUT_WH + x], s);
            orow[x] = s;
        }
    }
}

// ---------------------------------------------------------------------------
extern "C" void kernel_launch(void* const* d_in, const int* in_sizes, int n_in,
                              void* d_out, int out_size, void* d_ws, size_t ws_size,
                              hipStream_t stream) {
    const float* emb  = (const float*)d_in[0];
    const float* bank = (const float*)d_in[1];
    float* out = (float*)d_out;

    char* ws = (char*)d_ws;
    ull*   minpack = (ull*)(ws + WS_MINPACK);
    float* x2      = (float*)(ws + WS_X2);
    float* y2      = (float*)(ws + WS_Y2);
    float* pscore  = (float*)(ws + WS_PSCORE);
    float* bscore  = (float*)(ws + WS_BSCORE);
    int*   bmaxp   = (int*)(ws + WS_BMAXP);
    int*   bnn     = (int*)(ws + WS_BNN);
    ull*   cand    = (ull*)(ws + WS_CAND);
    int*   clist   = (int*)(ws + WS_CLIST);
    int*   ccnt    = (int*)(ws + WS_CCNT);
    ull*   emin    = (ull*)(ws + WS_EMIN);
    float* dnn     = (float*)(ws + WS_DNN);
    unsigned short* Apk = (unsigned short*)(ws + WS_APK);
    unsigned short* Bpk = (unsigned short*)(ws + WS_BPK);

    // 0: bf16-hi pack + sumsq + minpack init
    prep_kernel<<<(N_EMB + M_BANK) / 4, 256, 0, stream>>>(emb, bank, Apk, Bpk, x2, y2, minpack);
    // 1: approx MFMA distance + fused min/argmin (K=128)
    {
        dim3 grid(M_BANK / 128, N_EMB / 128);   // 256 x 49
        mfma_min_kernel<<<grid, 256, 0, stream>>>(Apk, Bpk, x2, y2, minpack);
    }
    // 2: pscore + candidate selection (certified superset of exact argmax)
    select_kernel<<<BATCH, 256, 0, stream>>>(minpack, pscore, clist, ccnt, emin);
    // 3: exact fp32 repair of candidate rows
    {
        dim3 grid(32, BATCH);
        repair_kernel<<<grid, 256, 0, stream>>>(emb, bank, x2, y2, clist, ccnt, emin);
    }
    // 4: exact bscore/bmaxp/bnn
    scorefix_kernel<<<BATCH, 64, 0, stream>>>(clist, ccnt, emin, bscore, bmaxp, bnn);
    // 5: d_nn
    dnn_kernel<<<M_BANK / 4, 256, 0, stream>>>(bank, y2, bnn, dnn);
    // 6: per-chunk top-9 candidates
    {
        dim3 grid(32, BATCH);
        topk_part_kernel<<<grid, 256, 0, stream>>>(dnn, cand);
    }
    // 7: role-branched final top-9+rescore (blocks 0..7) and blur (8..63)
    final_blur_kernel<<<64, 256, 0, stream>>>(cand, emb, bank, x2, y2, bscore, bmaxp, pscore, out);
}

// Round 8
// 418.352 us; speedup vs baseline: 2.2035x; 2.2035x over previous
//
#include <hip/hip_runtime.h>
#include <hip/hip_bf16.h>

// Problem constants (from setup_inputs)
#define N_EMB   6272
#define M_BANK  32768
#define D_DIM   128
#define KP      128      // bf16 row length (hi or lo plane)
#define BATCH   8
#define P_PATCH 784      // 6272 / 8
#define GRID_WH 28
#define OUT_WH  224
#define KNN     9
#define KSIZE   33
#define KRAD    16
#define NCAND   96       // exact-repair candidates per batch (top-96 by approx)

typedef unsigned long long ull;
typedef short bf16x8 __attribute__((ext_vector_type(8)));
typedef float f32x4  __attribute__((ext_vector_type(4)));

// ---------------- workspace layout (bytes) ----------------
#define WS_MINPACK 0          // u64[6272]        -> 50176
#define WS_X2      50176      // f32[6272]        -> 75264
#define WS_Y2      75264      // f32[32768]       -> 206336
#define WS_PSCORE  206336     // f32[6272]        -> 231424
#define WS_BSCORE  231424     // f32[8]
#define WS_BMAXP   231456     // i32[8]
#define WS_BNN     231488     // i32[8]
#define WS_CAND    231552     // u64[8*32*9]      -> 249984
#define WS_CLISTG  249984     // i32[768] global emb row ids -> 253056
#define WS_CX2     253056     // f32[768]         -> 256128
#define WS_CMIN    256128     // u64[768]         -> 262272
#define WS_DNN     262272     // f32[8*32768]     -> 1310848
#define WS_CAH     1310848    // u16[768*128]     -> 1507456
#define WS_CAL     1507456    // u16[768*128]     -> 1704064
#define WS_APK     1704064    // u16[6272*128]    -> 3309696   (emb hi)
#define WS_BPK     3309696    // u16[32768*128]   -> 11698304  (bank hi)
#define WS_BLO     11698304   // u16[32768*128]   -> 20086912  (bank lo)

__device__ __forceinline__ ull umin64(ull a, ull b) { return a < b ? a : b; }
__device__ __forceinline__ ull umax64(ull a, ull b) { return a > b ? a : b; }

__device__ __forceinline__ void gload_lds16(const void* g, void* l) {
    __builtin_amdgcn_global_load_lds(
        (const __attribute__((address_space(1))) void*)g,
        (__attribute__((address_space(3))) void*)l, 16, 0, 0);
}

// ---------------------------------------------------------------------------
// Kernel 0 (prep): bf16 packing + sum-of-squares + minpack init.
// One wave per row. emb -> Ahi; bank -> Bhi + Blo.
// ---------------------------------------------------------------------------
__global__ __launch_bounds__(256) void prep_kernel(
    const float* __restrict__ emb, const float* __restrict__ bank,
    unsigned short* __restrict__ Ahi, unsigned short* __restrict__ Bhi,
    unsigned short* __restrict__ Blo,
    float* __restrict__ x2, float* __restrict__ y2, ull* __restrict__ minpack)
{
    const int tid = threadIdx.x;
    int gi = blockIdx.x * 256 + tid;
    if (gi < N_EMB) minpack[gi] = ~0ull;

    const int w    = blockIdx.x * 4 + (tid >> 6);
    const int lane = tid & 63;
    float2 v;
    float* sq;
    if (w < N_EMB) {
        v = *(const float2*)&emb[(size_t)w * D_DIM + 2 * lane];
        __hip_bfloat16 h0 = __float2bfloat16(v.x);
        __hip_bfloat16 h1 = __float2bfloat16(v.y);
        unsigned hb0 = *(unsigned short*)&h0, hb1 = *(unsigned short*)&h1;
        *(unsigned*)&Ahi[(size_t)w * KP + 2 * lane] = hb0 | (hb1 << 16);
        sq = x2 + w;
    } else {
        int m = w - N_EMB;             // grid sized exactly -> m < M_BANK
        v = *(const float2*)&bank[(size_t)m * D_DIM + 2 * lane];
        __hip_bfloat16 h0 = __float2bfloat16(v.x);
        __hip_bfloat16 h1 = __float2bfloat16(v.y);
        __hip_bfloat16 l0 = __float2bfloat16(v.x - __bfloat162float(h0));
        __hip_bfloat16 l1 = __float2bfloat16(v.y - __bfloat162float(h1));
        unsigned hb0 = *(unsigned short*)&h0, hb1 = *(unsigned short*)&h1;
        unsigned lb0 = *(unsigned short*)&l0, lb1 = *(unsigned short*)&l1;
        *(unsigned*)&Bhi[(size_t)m * KP + 2 * lane] = hb0 | (hb1 << 16);
        *(unsigned*)&Blo[(size_t)m * KP + 2 * lane] = lb0 | (lb1 << 16);
        sq = y2 + m;
    }
    float s = fmaf(v.x, v.x, v.y * v.y);
    #pragma unroll
    for (int off = 32; off > 0; off >>= 1) s += __shfl_down(s, off, 64);
    if (lane == 0) *sq = s;
}

// ---------------------------------------------------------------------------
// Kernel 1: single-pass bf16-hi MFMA distance + fused min/argmin (approx map).
// 128x128 tile, 16x16x32 MFMA, K=128 (4 k-iters). R3-proven structure.
// ---------------------------------------------------------------------------
__global__ __launch_bounds__(256) void mfma_min_kernel(
    const unsigned short* __restrict__ Apk, const unsigned short* __restrict__ Bpk,
    const float* __restrict__ x2, const float* __restrict__ y2,
    ull* __restrict__ minpack)
{
    __shared__ __align__(16) unsigned short Asm_[128 * 32];  // 8 KB
    __shared__ __align__(16) unsigned short Bsm_[128 * 32];  // 8 KB

    const int tid  = threadIdx.x;
    const int lane = tid & 63;
    const int wave = tid >> 6;
    const int wr = wave >> 1, wc = wave & 1;
    const int n0 = blockIdx.y * 128;
    const int m0 = blockIdx.x * 128;

    const int srow = tid >> 2;   // 0..63 staging row
    const int sseg = tid & 3;    // 16B segment within 64B row-chunk

    const int qa = lane >> 4;    // k-quad
    const int ra = lane & 15;    // row-in-frag / col-in-C

    f32x4 acc[4][4];
    #pragma unroll
    for (int i = 0; i < 4; ++i)
        #pragma unroll
        for (int j = 0; j < 4; ++j)
            acc[i][j] = (f32x4){0.f, 0.f, 0.f, 0.f};

    for (int ks = 0; ks < KP; ks += 32) {
        __syncthreads();
        const size_t gA = (size_t)(n0 + srow) * KP + ks + sseg * 8;
        const size_t gB = (size_t)(m0 + srow) * KP + ks + sseg * 8;
        gload_lds16(Apk + gA,            &Asm_[srow * 32 + sseg * 8]);
        gload_lds16(Apk + gA + 64 * KP,  &Asm_[(srow + 64) * 32 + sseg * 8]);
        gload_lds16(Bpk + gB,            &Bsm_[srow * 32 + sseg * 8]);
        gload_lds16(Bpk + gB + 64 * KP,  &Bsm_[(srow + 64) * 32 + sseg * 8]);
        __syncthreads();

        bf16x8 af[4], bfr[4];
        #pragma unroll
        for (int i = 0; i < 4; ++i)
            af[i] = *(const bf16x8*)&Asm_[(wr * 64 + i * 16 + ra) * 32 + qa * 8];
        #pragma unroll
        for (int j = 0; j < 4; ++j)
            bfr[j] = *(const bf16x8*)&Bsm_[(wc * 64 + j * 16 + ra) * 32 + qa * 8];
        #pragma unroll
        for (int i = 0; i < 4; ++i)
            #pragma unroll
            for (int j = 0; j < 4; ++j)
                acc[i][j] = __builtin_amdgcn_mfma_f32_16x16x32_bf16(af[i], bfr[j], acc[i][j], 0, 0, 0);
    }

    // ---- epilogue: d2 = x2 + y2 - 2*dot, clamp, pack, reduce ----
    float y2v[4];
    #pragma unroll
    for (int j = 0; j < 4; ++j) y2v[j] = y2[m0 + wc * 64 + j * 16 + ra];

    __syncthreads();                 // all frag reads done; reuse Asm_ as red
    ull* red = (ull*)Asm_;           // [128 rows][2 col-halves]
    #pragma unroll
    for (int i = 0; i < 4; ++i) {
        #pragma unroll
        for (int r = 0; r < 4; ++r) {
            const int rowl = wr * 64 + i * 16 + qa * 4 + r;
            const float xv = x2[n0 + rowl];
            ull mn = ~0ull;
            #pragma unroll
            for (int j = 0; j < 4; ++j) {
                const int m = m0 + wc * 64 + j * 16 + ra;
                float d2 = fmaf(-2.0f, acc[i][j][r], xv + y2v[j]);
                d2 = fmaxf(d2, 0.0f);
                ull p = ((ull)__float_as_uint(d2) << 32) | (unsigned)m;
                mn = umin64(mn, p);
            }
            #pragma unroll
            for (int s = 1; s < 16; s <<= 1)
                mn = umin64(mn, (ull)__shfl_xor(mn, s, 64));
            if (ra == 0) red[rowl * 2 + wc] = mn;
        }
    }
    __syncthreads();
    if (tid < 128)
        atomicMin(&minpack[n0 + tid], umin64(red[tid * 2], red[tid * 2 + 1]));
}

// ---------------------------------------------------------------------------
// Kernel 2 (rank-select): per batch, write approx pscore map and select the
// exact top-NCAND patches by approx score via rank counting (deterministic,
// no atomics). Also init exact-min slots.
// ---------------------------------------------------------------------------
__global__ __launch_bounds__(256) void rank_select_kernel(
    const ull* __restrict__ minpack, float* __restrict__ pscore,
    int* __restrict__ clistg, ull* __restrict__ cmin)
{
    __shared__ unsigned keys[P_PATCH];
    const int b = blockIdx.x, tid = threadIdx.x;

    if (tid < NCAND) cmin[b * NCAND + tid] = ~0ull;

    for (int p = tid; p < P_PATCH; p += 256) {
        unsigned d2b = (unsigned)(minpack[b * P_PATCH + p] >> 32);
        keys[p] = d2b;                         // d2 >= 0: bits are order-preserving
        pscore[b * P_PATCH + p] = sqrtf(__uint_as_float(d2b));
    }
    __syncthreads();

    for (int p = tid; p < P_PATCH; p += 256) {
        const unsigned kp = keys[p];
        int rank = 0;
        for (int q = 0; q < P_PATCH; ++q) {
            unsigned kq = keys[q];
            rank += (kq > kp) | ((kq == kp) & (q < p));
        }
        if (rank < NCAND) clistg[b * NCAND + rank] = b * P_PATCH + p;
    }
}

// ---------------------------------------------------------------------------
// Kernel 3 (candpack): gather the 768 candidate embedding rows; pack bf16
// hi/lo planes + their x2. One wave per candidate row.
// ---------------------------------------------------------------------------
__global__ __launch_bounds__(256) void candpack_kernel(
    const float* __restrict__ emb, const float* __restrict__ x2,
    const int* __restrict__ clistg,
    unsigned short* __restrict__ CAh, unsigned short* __restrict__ CAl,
    float* __restrict__ cx2)
{
    const int tid = threadIdx.x;
    const int w = blockIdx.x * 4 + (tid >> 6);   // 0..767
    const int lane = tid & 63;
    const int g = clistg[w];
    float2 v = *(const float2*)&emb[(size_t)g * D_DIM + 2 * lane];
    __hip_bfloat16 h0 = __float2bfloat16(v.x);
    __hip_bfloat16 h1 = __float2bfloat16(v.y);
    __hip_bfloat16 l0 = __float2bfloat16(v.x - __bfloat162float(h0));
    __hip_bfloat16 l1 = __float2bfloat16(v.y - __bfloat162float(h1));
    unsigned hb0 = *(unsigned short*)&h0, hb1 = *(unsigned short*)&h1;
    unsigned lb0 = *(unsigned short*)&l0, lb1 = *(unsigned short*)&l1;
    *(unsigned*)&CAh[(size_t)w * KP + 2 * lane] = hb0 | (hb1 << 16);
    *(unsigned*)&CAl[(size_t)w * KP + 2 * lane] = lb0 | (lb1 << 16);
    if (lane == 0) cx2[w] = x2[g];
}

// ---------------------------------------------------------------------------
// Kernel 4 (repair): exact hi/lo MFMA distance + min/argmin for the 768
// candidate rows vs the full bank. Virtual K=384 over hi/lo planes:
// sections hi*hi, hi*lo, lo*hi (fp32-equivalent, same as R1-R5 proven path).
// Same proven 128x128 structure; grid (256 m-tiles, 6 row-tiles).
// ---------------------------------------------------------------------------
__global__ __launch_bounds__(256) void repair_kernel(
    const unsigned short* __restrict__ CAh, const unsigned short* __restrict__ CAl,
    const unsigned short* __restrict__ Bhi, const unsigned short* __restrict__ Blo,
    const float* __restrict__ cx2, const float* __restrict__ y2,
    ull* __restrict__ cmin)
{
    __shared__ __align__(16) unsigned short Asm_[128 * 32];  // 8 KB
    __shared__ __align__(16) unsigned short Bsm_[128 * 32];  // 8 KB

    const int tid  = threadIdx.x;
    const int lane = tid & 63;
    const int wave = tid >> 6;
    const int wr = wave >> 1, wc = wave & 1;
    const int n0 = blockIdx.y * 128;    // 0..5 -> 768 cand rows
    const int m0 = blockIdx.x * 128;

    const int srow = tid >> 2;
    const int sseg = tid & 3;
    const int qa = lane >> 4;
    const int ra = lane & 15;

    f32x4 acc[4][4];
    #pragma unroll
    for (int i = 0; i < 4; ++i)
        #pragma unroll
        for (int j = 0; j < 4; ++j)
            acc[i][j] = (f32x4){0.f, 0.f, 0.f, 0.f};

    for (int it = 0; it < 12; ++it) {
        const int sec = it >> 2;                 // 0: h*h, 1: h*l, 2: l*h
        const int ks  = (it & 3) * 32;
        const unsigned short* Ab = (sec == 2) ? CAl : CAh;
        const unsigned short* Bb = (sec == 1) ? Blo : Bhi;
        __syncthreads();
        const size_t gA = (size_t)(n0 + srow) * KP + ks + sseg * 8;
        const size_t gB = (size_t)(m0 + srow) * KP + ks + sseg * 8;
        gload_lds16(Ab + gA,            &Asm_[srow * 32 + sseg * 8]);
        gload_lds16(Ab + gA + 64 * KP,  &Asm_[(srow + 64) * 32 + sseg * 8]);
        gload_lds16(Bb + gB,            &Bsm_[srow * 32 + sseg * 8]);
        gload_lds16(Bb + gB + 64 * KP,  &Bsm_[(srow + 64) * 32 + sseg * 8]);
        __syncthreads();

        bf16x8 af[4], bfr[4];
        #pragma unroll
        for (int i = 0; i < 4; ++i)
            af[i] = *(const bf16x8*)&Asm_[(wr * 64 + i * 16 + ra) * 32 + qa * 8];
        #pragma unroll
        for (int j = 0; j < 4; ++j)
            bfr[j] = *(const bf16x8*)&Bsm_[(wc * 64 + j * 16 + ra) * 32 + qa * 8];
        #pragma unroll
        for (int i = 0; i < 4; ++i)
            #pragma unroll
            for (int j = 0; j < 4; ++j)
                acc[i][j] = __builtin_amdgcn_mfma_f32_16x16x32_bf16(af[i], bfr[j], acc[i][j], 0, 0, 0);
    }

    float y2v[4];
    #pragma unroll
    for (int j = 0; j < 4; ++j) y2v[j] = y2[m0 + wc * 64 + j * 16 + ra];

    __syncthreads();
    ull* red = (ull*)Asm_;
    #pragma unroll
    for (int i = 0; i < 4; ++i) {
        #pragma unroll
        for (int r = 0; r < 4; ++r) {
            const int rowl = wr * 64 + i * 16 + qa * 4 + r;
            const float xv = cx2[n0 + rowl];
            ull mn = ~0ull;
            #pragma unroll
            for (int j = 0; j < 4; ++j) {
                const int m = m0 + wc * 64 + j * 16 + ra;
                float d2 = fmaf(-2.0f, acc[i][j][r], xv + y2v[j]);
                d2 = fmaxf(d2, 0.0f);
                ull p = ((ull)__float_as_uint(d2) << 32) | (unsigned)m;
                mn = umin64(mn, p);
            }
            #pragma unroll
            for (int s = 1; s < 16; s <<= 1)
                mn = umin64(mn, (ull)__shfl_xor(mn, s, 64));
            if (ra == 0) red[rowl * 2 + wc] = mn;
        }
    }
    __syncthreads();
    if (tid < 128)
        atomicMin(&cmin[n0 + tid], umin64(red[tid * 2], red[tid * 2 + 1]));
}

// ---------------------------------------------------------------------------
// Kernel 5 (scorefix): per batch exact argmax over the NCAND repaired scores
// -> bscore, bmaxp, bnn. 128 threads/block.
// ---------------------------------------------------------------------------
__global__ __launch_bounds__(128) void scorefix_kernel(
    const int* __restrict__ clistg, const ull* __restrict__ cmin,
    float* __restrict__ bscore, int* __restrict__ bmaxp, int* __restrict__ bnn)
{
    __shared__ ull red[128];
    const int b = blockIdx.x, tid = threadIdx.x;
    ull key = 0, mine = 0;
    if (tid < NCAND) {
        mine = cmin[b * NCAND + tid];
        float sc = sqrtf(__uint_as_float((unsigned)(mine >> 32)));
        int p = clistg[b * NCAND + tid] - b * P_PATCH;
        key = ((ull)__float_as_uint(sc) << 32) | (unsigned)(p ^ 0xFFFFFFFFu);
    }
    red[tid] = key;
    __syncthreads();
    for (int s = 64; s > 0; s >>= 1) {
        if (tid < s) red[tid] = umax64(red[tid], red[tid + s]);
        __syncthreads();
    }
    ull win = red[0];
    if (tid == 0) {
        bscore[b] = __uint_as_float((unsigned)(win >> 32));
        bmaxp[b]  = (int)(((unsigned)(win & 0xFFFFFFFFu)) ^ 0xFFFFFFFFu);
    }
    if (tid < NCAND && key == win && key != 0)
        bnn[b] = (int)(mine & 0xFFFFFFFFu);
}

// ---------------------------------------------------------------------------
// Kernel 6: d_nn = dist(nn_sample[b], memory_bank) -> (8, M). 8192 blocks.
// ---------------------------------------------------------------------------
__global__ __launch_bounds__(256) void dnn_kernel(
    const float* __restrict__ bank, const float* __restrict__ y2,
    const int* __restrict__ bnn, float* __restrict__ dnn)
{
    __shared__ float nn[BATCH][D_DIM];
    __shared__ float nny2[BATCH];
    int tid = threadIdx.x;
    for (int i = tid; i < BATCH * D_DIM; i += 256) {
        int b = i >> 7, d = i & 127;
        nn[b][d] = bank[(size_t)bnn[b] * D_DIM + d];
    }
    if (tid < BATCH) nny2[tid] = y2[bnn[tid]];
    __syncthreads();

    int w = tid >> 6, lane = tid & 63;
    int m = blockIdx.x * 4 + w;
    float2 v = *(const float2*)&bank[(size_t)m * D_DIM + 2 * lane];
    float part[BATCH];
    #pragma unroll
    for (int b = 0; b < BATCH; ++b)
        part[b] = fmaf(v.x, nn[b][2 * lane], v.y * nn[b][2 * lane + 1]);
    #pragma unroll
    for (int b = 0; b < BATCH; ++b) {
        float s = part[b];
        #pragma unroll
        for (int off = 32; off > 0; off >>= 1) s += __shfl_down(s, off, 64);
        if (lane == 0) {
            float d2 = nny2[b] + y2[m] - 2.0f * s;
            dnn[b * M_BANK + m] = sqrtf(fmaxf(d2, 0.0f));
        }
    }
}

// ---------------------------------------------------------------------------
// Kernel 7: per-(batch, 1024-chunk) local top-9 of d_nn.
// ---------------------------------------------------------------------------
__global__ __launch_bounds__(256) void topk_part_kernel(
    const float* __restrict__ dnn, ull* __restrict__ cand)
{
    __shared__ ull vals[1024];
    __shared__ ull red[256];
    const int tid = threadIdx.x;
    const int b = blockIdx.y, ch = blockIdx.x;
    const int base = ch * 1024;

    #pragma unroll
    for (int j = 0; j < 4; ++j) {
        int i = base + tid + j * 256;
        vals[tid + j * 256] = ((ull)__float_as_uint(dnn[b * M_BANK + i]) << 32) | (unsigned)i;
    }
    __syncthreads();

    for (int k = 0; k < KNN; ++k) {
        ull local = vals[tid];
        #pragma unroll
        for (int j = 1; j < 4; ++j) local = umin64(local, vals[tid + j * 256]);
        red[tid] = local;
        __syncthreads();
        for (int s = 128; s > 0; s >>= 1) {
            if (tid < s) red[tid] = umin64(red[tid], red[tid + s]);
            __syncthreads();
        }
        ull win = red[0];
        if (tid == 0) cand[(b * 32 + ch) * KNN + k] = win;
        #pragma unroll
        for (int j = 0; j < 4; ++j)
            if (vals[tid + j * 256] == win) vals[tid + j * 256] = ~0ull;
        __syncthreads();
    }
}

// ---------------------------------------------------------------------------
// Kernel 8 (role-branched): blocks 0..7 = final top-9 + rescore -> out[0..7];
// blocks 8..63 = fused resize+blur bands -> out[8..].
// ---------------------------------------------------------------------------
__device__ __forceinline__ int refl224(int i) {
    if (i < 0) i = -i;
    if (i >= OUT_WH) i = 2 * (OUT_WH - 1) - i;
    return i;
}

__global__ __launch_bounds__(256) void final_blur_kernel(
    const ull* __restrict__ cand,
    const float* __restrict__ emb, const float* __restrict__ bank,
    const float* __restrict__ x2, const float* __restrict__ y2,
    const float* __restrict__ bscore, const int* __restrict__ bmaxp,
    const float* __restrict__ pscore, float* __restrict__ out)
{
    __shared__ __align__(16) char smem_raw[57344];
    const int tid = threadIdx.x;

    if (blockIdx.x < 8) {
        // ---------------- role A: final top-9 + rescore ----------------
        ull* vals    = (ull*)smem_raw;          // 512
        ull* red     = vals + 512;              // 256
        int* chosen  = (int*)(red + 256);       // KNN (pad 16)
        float* dists = (float*)(chosen + 16);   // KNN
        const int b = blockIdx.x;

        vals[tid]       = (tid < 32 * KNN) ? cand[b * 32 * KNN + tid] : ~0ull;
        vals[tid + 256] = (tid + 256 < 32 * KNN) ? cand[b * 32 * KNN + tid + 256] : ~0ull;
        __syncthreads();

        for (int k = 0; k < KNN; ++k) {
            red[tid] = umin64(vals[tid], vals[tid + 256]);
            __syncthreads();
            for (int s = 128; s > 0; s >>= 1) {
                if (tid < s) red[tid] = umin64(red[tid], red[tid + s]);
                __syncthreads();
            }
            ull win = red[0];
            if (tid == 0) chosen[k] = (int)(win & 0xFFFFFFFFu);
            if (vals[tid] == win) vals[tid] = ~0ull;
            if (vals[tid + 256] == win) vals[tid + 256] = ~0ull;
            __syncthreads();
        }

        const int e = b * P_PATCH + bmaxp[b];
        if (tid < KNN) {
            const float* mf = emb + (size_t)e * D_DIM;
            const float* ms = bank + (size_t)chosen[tid] * D_DIM;
            float dot = 0.0f;
            for (int d = 0; d < D_DIM; ++d) dot = fmaf(mf[d], ms[d], dot);
            float d2 = x2[e] - 2.0f * dot + y2[chosen[tid]];
            dists[tid] = sqrtf(fmaxf(d2, 0.0f));
        }
        __syncthreads();
        if (tid == 0) {
            float mx = dists[0];
            for (int k = 1; k < KNN; ++k) mx = fmaxf(mx, dists[k]);
            float s = 0.0f;
            for (int k = 0; k < KNN; ++k) s += expf(dists[k] - mx);
            float w = 1.0f - expf(dists[0] - mx) / s;
            out[b] = w * bscore[b];
        }
    } else {
        // ---------------- role B: fused resize + separable blur ----------------
        float* q    = (float*)smem_raw;         // 28*224
        float* hq   = q + GRID_WH * OUT_WH;     // 28*224
        float* ps   = hq + GRID_WH * OUT_WH;    // 784
        float* wrow = ps + P_PATCH;             // 32*28
        float* g    = wrow + 32 * GRID_WH;      // 33

        const int idx  = blockIdx.x - 8;
        const int band = idx % 7;               // 0..6
        const int b    = idx / 7;               // 0..7

        if (tid < KSIZE) {
            float x = (tid - KRAD) * 0.25f;     // / SIGMA=4
            g[tid] = __expf(-0.5f * x * x);
        }
        for (int i = tid; i < P_PATCH; i += 256) ps[i] = pscore[b * P_PATCH + i];
        __syncthreads();
        if (tid == 0) {
            float s = 0.0f;
            for (int i = 0; i < KSIZE; ++i) s += g[i];
            float inv = 1.0f / s;
            for (int i = 0; i < KSIZE; ++i) g[i] *= inv;
        }
        __syncthreads();

        for (int i = tid; i < GRID_WH * OUT_WH; i += 256) {
            int gy = i / OUT_WH, x = i - gy * OUT_WH;
            float cx = (2 * x - 7) * 0.0625f;
            int ix = (int)floorf(cx); float fx = cx - ix;
            int x0 = min(max(ix, 0), GRID_WH - 1), x1 = min(max(ix + 1, 0), GRID_WH - 1);
            q[i] = ps[gy * GRID_WH + x0] * (1.0f - fx) + ps[gy * GRID_WH + x1] * fx;
        }

        if (tid < 32) {
            int y = band * 32 + tid;
            for (int gy = 0; gy < GRID_WH; ++gy) wrow[tid * GRID_WH + gy] = 0.0f;
            for (int t = 0; t < KSIZE; ++t) {
                int yy = refl224(y - KRAD + t);
                float cy = (2 * yy - 7) * 0.0625f;
                int iy = (int)floorf(cy); float fy = cy - iy;
                int y0 = min(max(iy, 0), GRID_WH - 1), y1 = min(max(iy + 1, 0), GRID_WH - 1);
                wrow[tid * GRID_WH + y0] += g[t] * (1.0f - fy);
                wrow[tid * GRID_WH + y1] += g[t] * fy;
            }
        }
        __syncthreads();

        for (int i = tid; i < GRID_WH * OUT_WH; i += 256) {
            int gy = i / OUT_WH, x = i - gy * OUT_WH;
            float s = 0.0f;
            #pragma unroll
            for (int t = 0; t < KSIZE; ++t)
                s = fmaf(g[t], q[gy * OUT_WH + refl224(x - KRAD + t)], s);
            hq[i] = s;
        }
        __syncthreads();

        const int yl = tid >> 3;                 // 0..31
        const int xbase = (tid & 7) * 28;        // 8 groups x 28 px
        const int y = band * 32 + yl;
        float* orow = out + BATCH + ((size_t)b * OUT_WH + y) * OUT_WH;
        for (int i = 0; i < 28; ++i) {
            int x = xbase + i;
            float s = 0.0f;
            #pragma unroll
            for (int gy = 0; gy < GRID_WH; ++gy)
                s = fmaf(wrow[yl * GRID_WH + gy], hq[gy * OUT_WH + x], s);
            orow[x] = s;
        }
    }
}

// ---------------------------------------------------------------------------
extern "C" void kernel_launch(void* const* d_in, const int* in_sizes, int n_in,
                              void* d_out, int out_size, void* d_ws, size_t ws_size,
                              hipStream_t stream) {
    const float* emb  = (const float*)d_in[0];
    const float* bank = (const float*)d_in[1];
    float* out = (float*)d_out;

    char* ws = (char*)d_ws;
    ull*   minpack = (ull*)(ws + WS_MINPACK);
    float* x2      = (float*)(ws + WS_X2);
    float* y2      = (float*)(ws + WS_Y2);
    float* pscore  = (float*)(ws + WS_PSCORE);
    float* bscore  = (float*)(ws + WS_BSCORE);
    int*   bmaxp   = (int*)(ws + WS_BMAXP);
    int*   bnn     = (int*)(ws + WS_BNN);
    ull*   cand    = (ull*)(ws + WS_CAND);
    int*   clistg  = (int*)(ws + WS_CLISTG);
    float* cx2     = (float*)(ws + WS_CX2);
    ull*   cmin    = (ull*)(ws + WS_CMIN);
    float* dnn     = (float*)(ws + WS_DNN);
    unsigned short* CAh = (unsigned short*)(ws + WS_CAH);
    unsigned short* CAl = (unsigned short*)(ws + WS_CAL);
    unsigned short* Ahi = (unsigned short*)(ws + WS_APK);
    unsigned short* Bhi = (unsigned short*)(ws + WS_BPK);
    unsigned short* Blo = (unsigned short*)(ws + WS_BLO);

    // 0: bf16 pack (emb hi; bank hi+lo) + sumsq + minpack init
    prep_kernel<<<(N_EMB + M_BANK) / 4, 256, 0, stream>>>(emb, bank, Ahi, Bhi, Blo, x2, y2, minpack);
    // 1: approx MFMA distance + fused min/argmin (K=128)
    {
        dim3 grid(M_BANK / 128, N_EMB / 128);   // 256 x 49
        mfma_min_kernel<<<grid, 256, 0, stream>>>(Ahi, Bhi, x2, y2, minpack);
    }
    // 2: pscore map + exact top-96 candidate selection by rank
    rank_select_kernel<<<BATCH, 256, 0, stream>>>(minpack, pscore, clistg, cmin);
    // 3: gather + hi/lo pack candidate rows
    candpack_kernel<<<BATCH * NCAND / 4, 256, 0, stream>>>(emb, x2, clistg, CAh, CAl, cx2);
    // 4: exact hi/lo MFMA repair of candidate rows (virtual K=384)
    {
        dim3 grid(M_BANK / 128, BATCH * NCAND / 128);   // 256 x 6
        repair_kernel<<<grid, 256, 0, stream>>>(CAh, CAl, Bhi, Blo, cx2, y2, cmin);
    }
    // 5: exact bscore/bmaxp/bnn
    scorefix_kernel<<<BATCH, 128, 0, stream>>>(clistg, cmin, bscore, bmaxp, bnn);
    // 6: d_nn
    dnn_kernel<<<M_BANK / 4, 256, 0, stream>>>(bank, y2, bnn, dnn);
    // 7: per-chunk top-9 candidates
    {
        dim3 grid(32, BATCH);
        topk_part_kernel<<<grid, 256, 0, stream>>>(dnn, cand);
    }
    // 8: role-branched final top-9+rescore (blocks 0..7) and blur (8..63)
    final_blur_kernel<<<64, 256, 0, stream>>>(cand, emb, bank, x2, y2, bscore, bmaxp, pscore, out);
}